// Round 2
// baseline (233.818 us; speedup 1.0000x reference)
//
#include <hip/hip_runtime.h>

// out[b,h] = sum_{i,j} cb[h, i*64+j] * in1[b,i] * in2[b,j]
// B = 4096, dim1 = dim2 = 64, H = 4096.
//
// cb block structure (from ls1 = ls2 = [0]*4+[1]*4+[2]*4+[3]*4):
//   rows grouped by l3 ascending; within l3, (l1,l2) value-pairs sorted by
//   key = l1*3+l2 (stable: ties keep slot1-major insertion order -> smaller
//   l1 first: at l3=2 (1,3) before (2,0); at l3=3 (2,3) before (3,0));
//   each value pair expands to 16 slot pairs x (2*l3+1) rows.
// Row h's nonzeros live at cols (i1+m1)*64 + (i2+m2), m1<2*l1+1, m2<2*l2+1.

#define PAD 65   // 64 + 1 padding: conflict-free LDS columns

__constant__ int   kStart[7] = {0, 64, 496, 1376, 2496, 3360, 3888};
__constant__ unsigned kMagic[7] = {262144u, 87382u, 52429u, 37450u, 29128u, 23832u, 20165u}; // 2^18/d rounded up, d=2*l3+1
__constant__ int   kVpOff[7] = {0, 4, 13, 24, 34, 40, 43};
__constant__ unsigned char kVp[44] = {
  // l3=0: (0,0)(1,1)(2,2)(3,3)
  0, 5, 10, 15,
  // l3=1: (0,1)(1,0)(1,1)(1,2)(2,1)(2,2)(2,3)(3,2)(3,3)
  1, 4, 5, 6, 9, 10, 11, 14, 15,
  // l3=2: (0,2)(1,1)(1,2)(1,3)(2,0)(2,1)(2,2)(2,3)(3,1)(3,2)(3,3)
  2, 5, 6, 7, 8, 9, 10, 11, 13, 14, 15,
  // l3=3: (0,3)(1,2)(1,3)(2,1)(2,2)(2,3)(3,0)(3,1)(3,2)(3,3)
  3, 6, 7, 9, 10, 11, 12, 13, 14, 15,
  // l3=4: (1,3)(2,2)(2,3)(3,1)(3,2)(3,3)
  7, 10, 11, 13, 14, 15,
  // l3=5: (2,3)(3,2)(3,3)
  11, 14, 15,
  // l3=6: (3,3)
  15};
__constant__ int kBase[4] = {0, 4, 16, 36};  // offset of first slot of each l

template <int N1, int N2>
__device__ __forceinline__ float inner_tp(const float* __restrict__ row,
                                          const float* __restrict__ s1,
                                          const float* __restrict__ s2,
                                          int i1, int i2, int t) {
  float bb[N2];
#pragma unroll
  for (int j = 0; j < N2; ++j) bb[j] = s2[(i2 + j) * PAD + t];
  float acc0 = 0.f, acc1 = 0.f;
#pragma unroll
  for (int i = 0; i < N1; ++i) {
    float a = s1[(i1 + i) * PAD + t];
    const float* rr = row + (i1 + i) * 64 + i2;   // wave-uniform -> s_load
    float tsum = rr[0] * bb[0];
#pragma unroll
    for (int j = 1; j < N2; ++j) tsum = fmaf(rr[j], bb[j], tsum);
    if (i & 1) acc1 = fmaf(a, tsum, acc1);
    else       acc0 = fmaf(a, tsum, acc0);
  }
  return acc0 + acc1;
}

__global__ __launch_bounds__(256) void tp_kernel(
    const float* __restrict__ in1, const float* __restrict__ in2,
    const float* __restrict__ cb, float* __restrict__ out) {
  __shared__ float s1[64 * PAD];   // [dim][batch] transposed, padded
  __shared__ float s2[64 * PAD];
  __shared__ float so[64 * PAD];   // [h_local][batch] output tile

  const int tid = threadIdx.x;
  const int b0 = blockIdx.x << 6;   // batch tile (64)
  const int h0 = blockIdx.y << 6;   // h tile (64)

  // ---- stage in1/in2 tiles into LDS, transposed [d][b] ----
  const float4* g1 = reinterpret_cast<const float4*>(in1 + (size_t)b0 * 64);
  const float4* g2 = reinterpret_cast<const float4*>(in2 + (size_t)b0 * 64);
#pragma unroll
  for (int r = 0; r < 4; ++r) {
    int idx4 = r * 256 + tid;          // float4 index into 64x64 tile
    float4 v1 = g1[idx4];
    float4 v2 = g2[idx4];
    int bl = idx4 >> 4;                // batch row (16 float4 per row)
    int d0 = (idx4 & 15) << 2;         // dim start
    s1[(d0 + 0) * PAD + bl] = v1.x; s1[(d0 + 1) * PAD + bl] = v1.y;
    s1[(d0 + 2) * PAD + bl] = v1.z; s1[(d0 + 3) * PAD + bl] = v1.w;
    s2[(d0 + 0) * PAD + bl] = v2.x; s2[(d0 + 1) * PAD + bl] = v2.y;
    s2[(d0 + 2) * PAD + bl] = v2.z; s2[(d0 + 3) * PAD + bl] = v2.w;
  }
  __syncthreads();

  const int w = tid >> 6;   // wave id: owns h_local [w*16, w*16+16)
  const int t = tid & 63;   // lane = batch element

#pragma unroll 1
  for (int hh = 0; hh < 16; ++hh) {
    int h = __builtin_amdgcn_readfirstlane(h0 + (w << 4) + hh);  // wave-uniform
    // ---- h -> (i1, i2, l1, l2) closed form ----
    int l3 = (h >= 64) + (h >= 496) + (h >= 1376) + (h >= 2496) + (h >= 3360) + (h >= 3888);
    unsigned hl = (unsigned)(h - kStart[l3]);
    int pair = (int)((hl * kMagic[l3]) >> 18);   // hl / (2*l3+1), exact in range
    int slot = pair & 15;
    int vp   = pair >> 4;
    int l1l2 = (int)kVp[kVpOff[l3] + vp];
    int l1 = l1l2 >> 2, l2 = l1l2 & 3;
    int i1 = kBase[l1] + (slot >> 2) * (2 * l1 + 1);
    int i2 = kBase[l2] + (slot & 3) * (2 * l2 + 1);
    const float* row = cb + (size_t)h * 4096;

    float acc = 0.f;
#define TP_CASE(L1, L2) \
    case (L1 * 4 + L2): acc = inner_tp<2 * L1 + 1, 2 * L2 + 1>(row, s1, s2, i1, i2, t); break;
    switch (l1l2) {
      TP_CASE(0, 0) TP_CASE(0, 1) TP_CASE(0, 2) TP_CASE(0, 3)
      TP_CASE(1, 0) TP_CASE(1, 1) TP_CASE(1, 2) TP_CASE(1, 3)
      TP_CASE(2, 0) TP_CASE(2, 1) TP_CASE(2, 2) TP_CASE(2, 3)
      TP_CASE(3, 0) TP_CASE(3, 1) TP_CASE(3, 2) TP_CASE(3, 3)
      default: break;
    }
#undef TP_CASE
    so[(w * 16 + hh) * PAD + t] = acc;
  }
  __syncthreads();

  // ---- store 64x64 tile: each lane owns 16 floats of a batch row ----
  const int bl = tid >> 2;            // batch row 0..63
  const int hseg = (tid & 3) << 4;    // 0,16,32,48
  float* outp = out + (size_t)(b0 + bl) * 4096 + h0 + hseg;
#pragma unroll
  for (int k = 0; k < 4; ++k) {
    float4 v;
    v.x = so[(hseg + 4 * k + 0) * PAD + bl];
    v.y = so[(hseg + 4 * k + 1) * PAD + bl];
    v.z = so[(hseg + 4 * k + 2) * PAD + bl];
    v.w = so[(hseg + 4 * k + 3) * PAD + bl];
    reinterpret_cast<float4*>(outp)[k] = v;
  }
}

extern "C" void kernel_launch(void* const* d_in, const int* in_sizes, int n_in,
                              void* d_out, int out_size, void* d_ws, size_t ws_size,
                              hipStream_t stream) {
  const float* in1 = (const float*)d_in[0];
  const float* in2 = (const float*)d_in[1];
  const float* cb  = (const float*)d_in[2];
  float* out = (float*)d_out;
  (void)in_sizes; (void)n_in; (void)out_size; (void)d_ws; (void)ws_size;
  dim3 grid(64, 64);   // (batch tiles, h tiles)
  tp_kernel<<<grid, dim3(256), 0, stream>>>(in1, in2, cb, out);
}

// Round 3
// 182.705 us; speedup vs baseline: 1.2798x; 1.2798x over previous
//
#include <hip/hip_runtime.h>

// out[b,h] = sum_{i,j} cb[h, i*64+j] * in1[b,i] * in2[b,j]
// B = 4096, dim1 = dim2 = 64, H = 4096.
//
// Round-2 structure:
//   prep_kernel: compact cb's per-row nonzeros (row h has n1*n2 <= 49 of
//     them, in n1 runs of n2, stride 64) into table[h][0..63] in d_ws.
//   tp_kernel:  per wave, one coalesced load per row (lane = entry idx),
//     depth-2 pipelined across the 16 rows; cb operands come from
//     v_readlane at compile-time lanes inside the templated switch.
//     No s_loads, no per-iteration scalar-memory latency chain.

#define PAD 65   // 64 + 1 padding: conflict-free LDS columns

__constant__ int   kStart[7] = {0, 64, 496, 1376, 2496, 3360, 3888};
__constant__ unsigned kMagic[7] = {262144u, 87382u, 52429u, 37450u, 29128u, 23832u, 20165u}; // 2^18/d rounded up, d=2*l3+1
__constant__ int   kVpOff[7] = {0, 4, 13, 24, 34, 40, 43};
__constant__ unsigned char kVp[44] = {
  // l3=0: (0,0)(1,1)(2,2)(3,3)
  0, 5, 10, 15,
  // l3=1: (0,1)(1,0)(1,1)(1,2)(2,1)(2,2)(2,3)(3,2)(3,3)
  1, 4, 5, 6, 9, 10, 11, 14, 15,
  // l3=2: (0,2)(1,1)(1,2)(1,3)(2,0)(2,1)(2,2)(2,3)(3,1)(3,2)(3,3)
  2, 5, 6, 7, 8, 9, 10, 11, 13, 14, 15,
  // l3=3: (0,3)(1,2)(1,3)(2,1)(2,2)(2,3)(3,0)(3,1)(3,2)(3,3)
  3, 6, 7, 9, 10, 11, 12, 13, 14, 15,
  // l3=4: (1,3)(2,2)(2,3)(3,1)(3,2)(3,3)
  7, 10, 11, 13, 14, 15,
  // l3=5: (2,3)(3,2)(3,3)
  11, 14, 15,
  // l3=6: (3,3)
  15};
__constant__ int kBase[4] = {0, 4, 16, 36};  // offset of first slot of each l

__device__ __forceinline__ void decode_h(int h, int& i1, int& i2,
                                         int& n1, int& n2, int& l1l2) {
  int l3 = (h >= 64) + (h >= 496) + (h >= 1376) + (h >= 2496) + (h >= 3360) + (h >= 3888);
  unsigned hl = (unsigned)(h - kStart[l3]);
  int pair = (int)((hl * kMagic[l3]) >> 18);   // hl / (2*l3+1), exact in range
  int slot = pair & 15;
  int vp   = pair >> 4;
  l1l2 = (int)kVp[kVpOff[l3] + vp];
  int l1 = l1l2 >> 2, l2 = l1l2 & 3;
  n1 = 2 * l1 + 1;
  n2 = 2 * l2 + 1;
  i1 = kBase[l1] + (slot >> 2) * n1;
  i2 = kBase[l2] + (slot & 3) * n2;
}

// ---- prep: table[h][e] = cb[h, (i1 + e/n2)*64 + i2 + e%n2], 0-padded ----
__global__ __launch_bounds__(256) void prep_kernel(const float* __restrict__ cb,
                                                   float* __restrict__ table) {
  int idx = blockIdx.x * 256 + threadIdx.x;   // 1024 blocks -> 262144 = 4096*64
  int h = idx >> 6, e = idx & 63;
  int i1, i2, n1, n2, c;
  decode_h(h, i1, i2, n1, n2, c);
  unsigned mg = (n2 == 1) ? 65536u : (n2 == 3) ? 21846u : (n2 == 5) ? 13108u : 9363u;
  int qi = (int)(((unsigned)e * mg) >> 16);   // e / n2, exact for e < 64
  int rj = e - qi * n2;
  float v = 0.f;
  if (e < n1 * n2) v = cb[(size_t)h * 4096 + (i1 + qi) * 64 + (i2 + rj)];
  table[(size_t)h * 64 + e] = v;
}

__device__ __forceinline__ float lane_bcast(float v, int l) {
  union { float f; int i; } u;
  u.f = v;
  u.i = __builtin_amdgcn_readlane(u.i, l);
  return u.f;
}

template <int N1, int N2>
__device__ __forceinline__ float inner_tp(float vrow,
                                          const float* __restrict__ s1,
                                          const float* __restrict__ s2,
                                          int i1, int i2, int t) {
  float bb[N2];
#pragma unroll
  for (int j = 0; j < N2; ++j) bb[j] = s2[(i2 + j) * PAD + t];
  float acc0 = 0.f, acc1 = 0.f;
#pragma unroll
  for (int i = 0; i < N1; ++i) {
    float a = s1[(i1 + i) * PAD + t];
    float tsum = lane_bcast(vrow, i * N2) * bb[0];
#pragma unroll
    for (int j = 1; j < N2; ++j) tsum = fmaf(lane_bcast(vrow, i * N2 + j), bb[j], tsum);
    if (i & 1) acc1 = fmaf(a, tsum, acc1);
    else       acc0 = fmaf(a, tsum, acc0);
  }
  return acc0 + acc1;
}

__global__ __launch_bounds__(256) void tp_kernel(
    const float* __restrict__ in1, const float* __restrict__ in2,
    const float* __restrict__ table, float* __restrict__ out) {
  __shared__ float s1[64 * PAD];   // [dim][batch] transposed, padded
  __shared__ float s2[64 * PAD];
  __shared__ float so[64 * PAD];   // [h_local][batch] output tile

  const int tid = threadIdx.x;
  const int b0 = blockIdx.x << 6;   // batch tile (64)
  const int h0 = blockIdx.y << 6;   // h tile (64)

  // ---- stage in1/in2 tiles into LDS, transposed [d][b] ----
  const float4* g1 = reinterpret_cast<const float4*>(in1 + (size_t)b0 * 64);
  const float4* g2 = reinterpret_cast<const float4*>(in2 + (size_t)b0 * 64);
#pragma unroll
  for (int r = 0; r < 4; ++r) {
    int idx4 = r * 256 + tid;          // float4 index into 64x64 tile
    float4 v1 = g1[idx4];
    float4 v2 = g2[idx4];
    int bl = idx4 >> 4;                // batch row (16 float4 per row)
    int d0 = (idx4 & 15) << 2;         // dim start
    s1[(d0 + 0) * PAD + bl] = v1.x; s1[(d0 + 1) * PAD + bl] = v1.y;
    s1[(d0 + 2) * PAD + bl] = v1.z; s1[(d0 + 3) * PAD + bl] = v1.w;
    s2[(d0 + 0) * PAD + bl] = v2.x; s2[(d0 + 1) * PAD + bl] = v2.y;
    s2[(d0 + 2) * PAD + bl] = v2.z; s2[(d0 + 3) * PAD + bl] = v2.w;
  }
  __syncthreads();

  const int w = tid >> 6;   // wave id: owns h_local [w*16, w*16+16)
  const int t = tid & 63;   // lane = batch element

  // wave's 16 table rows; lane t holds entry t of each row
  const float* tb = table + ((size_t)(h0 + (w << 4)) << 6) + t;
  float cur = tb[0];
#pragma unroll 1
  for (int hh = 0; hh < 16; ++hh) {
    float nxt = tb[(hh + 1) << 6];    // depth-2 pipeline (last read hits pad row)
    int h = __builtin_amdgcn_readfirstlane(h0 + (w << 4) + hh);  // wave-uniform
    int i1, i2, n1, n2, l1l2;
    decode_h(h, i1, i2, n1, n2, l1l2);

    float acc = 0.f;
#define TP_CASE(L1, L2) \
    case (L1 * 4 + L2): acc = inner_tp<2 * L1 + 1, 2 * L2 + 1>(cur, s1, s2, i1, i2, t); break;
    switch (l1l2) {
      TP_CASE(0, 0) TP_CASE(0, 1) TP_CASE(0, 2) TP_CASE(0, 3)
      TP_CASE(1, 0) TP_CASE(1, 1) TP_CASE(1, 2) TP_CASE(1, 3)
      TP_CASE(2, 0) TP_CASE(2, 1) TP_CASE(2, 2) TP_CASE(2, 3)
      TP_CASE(3, 0) TP_CASE(3, 1) TP_CASE(3, 2) TP_CASE(3, 3)
      default: break;
    }
#undef TP_CASE
    so[(w * 16 + hh) * PAD + t] = acc;
    cur = nxt;
  }
  __syncthreads();

  // ---- store 64x64 tile: each lane owns 16 floats of a batch row ----
  const int bl = tid >> 2;            // batch row 0..63
  const int hseg = (tid & 3) << 4;    // 0,16,32,48
  float* outp = out + (size_t)(b0 + bl) * 4096 + h0 + hseg;
#pragma unroll
  for (int k = 0; k < 4; ++k) {
    float4 v;
    v.x = so[(hseg + 4 * k + 0) * PAD + bl];
    v.y = so[(hseg + 4 * k + 1) * PAD + bl];
    v.z = so[(hseg + 4 * k + 2) * PAD + bl];
    v.w = so[(hseg + 4 * k + 3) * PAD + bl];
    reinterpret_cast<float4*>(outp)[k] = v;
  }
}

extern "C" void kernel_launch(void* const* d_in, const int* in_sizes, int n_in,
                              void* d_out, int out_size, void* d_ws, size_t ws_size,
                              hipStream_t stream) {
  const float* in1 = (const float*)d_in[0];
  const float* in2 = (const float*)d_in[1];
  const float* cb  = (const float*)d_in[2];
  float* out = (float*)d_out;
  float* table = (float*)d_ws;   // needs 4097*64*4 B ~= 1.05 MB (last row is
                                 // read-but-unused pipeline padding)
  (void)in_sizes; (void)n_in; (void)out_size; (void)ws_size;
  prep_kernel<<<1024, 256, 0, stream>>>(cb, table);
  tp_kernel<<<dim3(64, 64), 256, 0, stream>>>(in1, in2, table, out);
}

// Round 4
// 158.970 us; speedup vs baseline: 1.4708x; 1.1493x over previous
//
#include <hip/hip_runtime.h>

// out[b,h] = sum_{i,j} cb[h, i*64+j] * in1[b,i] * in2[b,j]
// B = 4096, dim1 = dim2 = 64, H = 4096.
//
// Round-3 structure:
//   prep_kernel: compact cb row nonzeros into table[h][0..63] (d_ws).
//   tp_kernel: 512 threads (8 waves), 64b x 64h tile per block.
//     - wave w owns rows w+8k (stride-8 interleave -> balanced waves)
//     - so is a 16-row quarter tile, flushed 4x -> LDS 37.4KB -> 4 blk/CU
//     - cb rows prefetched phase-ahead into named regs (no global latency
//       in compute chain); values broadcast via v_readlane at const lanes.

#define PAD 65   // 64 + 1 padding: conflict-free LDS columns

__constant__ int   kStart[7] = {0, 64, 496, 1376, 2496, 3360, 3888};
__constant__ unsigned kMagic[7] = {262144u, 87382u, 52429u, 37450u, 29128u, 23832u, 20165u}; // 2^18/d rounded up, d=2*l3+1
__constant__ int   kVpOff[7] = {0, 4, 13, 24, 34, 40, 43};
__constant__ unsigned char kVp[44] = {
  0, 5, 10, 15,                                  // l3=0
  1, 4, 5, 6, 9, 10, 11, 14, 15,                 // l3=1
  2, 5, 6, 7, 8, 9, 10, 11, 13, 14, 15,          // l3=2 ((1,3) before (2,0))
  3, 6, 7, 9, 10, 11, 12, 13, 14, 15,            // l3=3 ((2,3) before (3,0))
  7, 10, 11, 13, 14, 15,                         // l3=4
  11, 14, 15,                                    // l3=5
  15};                                           // l3=6
__constant__ int kBase[4] = {0, 4, 16, 36};  // offset of first slot of each l

__device__ __forceinline__ void decode_h(int h, int& i1, int& i2,
                                         int& n1, int& n2, int& l1l2) {
  int l3 = (h >= 64) + (h >= 496) + (h >= 1376) + (h >= 2496) + (h >= 3360) + (h >= 3888);
  unsigned hl = (unsigned)(h - kStart[l3]);
  int pair = (int)((hl * kMagic[l3]) >> 18);   // hl / (2*l3+1), exact in range
  int slot = pair & 15;
  int vp   = pair >> 4;
  l1l2 = (int)kVp[kVpOff[l3] + vp];
  int l1 = l1l2 >> 2, l2 = l1l2 & 3;
  n1 = 2 * l1 + 1;
  n2 = 2 * l2 + 1;
  i1 = kBase[l1] + (slot >> 2) * n1;
  i2 = kBase[l2] + (slot & 3) * n2;
}

// ---- prep: table[h][e] = cb[h, (i1 + e/n2)*64 + i2 + e%n2], 0-padded ----
__global__ __launch_bounds__(256) void prep_kernel(const float* __restrict__ cb,
                                                   float* __restrict__ table) {
  int idx = blockIdx.x * 256 + threadIdx.x;   // 1024 blocks -> 262144 = 4096*64
  int h = idx >> 6, e = idx & 63;
  int i1, i2, n1, n2, c;
  decode_h(h, i1, i2, n1, n2, c);
  unsigned mg = (n2 == 1) ? 65536u : (n2 == 3) ? 21846u : (n2 == 5) ? 13108u : 9363u;
  int qi = (int)(((unsigned)e * mg) >> 16);   // e / n2, exact for e < 64
  int rj = e - qi * n2;
  float v = 0.f;
  if (e < n1 * n2) v = cb[(size_t)h * 4096 + (i1 + qi) * 64 + (i2 + rj)];
  table[(size_t)h * 64 + e] = v;
}

__device__ __forceinline__ float lane_bcast(float v, int l) {
  union { float f; int i; } u;
  u.f = v;
  u.i = __builtin_amdgcn_readlane(u.i, l);
  return u.f;
}

template <int N1, int N2>
__device__ __forceinline__ float inner_tp(float vrow,
                                          const float* __restrict__ s1,
                                          const float* __restrict__ s2,
                                          int i1, int i2, int t) {
  float bb[N2];
#pragma unroll
  for (int j = 0; j < N2; ++j) bb[j] = s2[(i2 + j) * PAD + t];
  float acc0 = 0.f, acc1 = 0.f;
#pragma unroll
  for (int i = 0; i < N1; ++i) {
    float a = s1[(i1 + i) * PAD + t];
    float tsum = lane_bcast(vrow, i * N2) * bb[0];
#pragma unroll
    for (int j = 1; j < N2; ++j) tsum = fmaf(lane_bcast(vrow, i * N2 + j), bb[j], tsum);
    if (i & 1) acc1 = fmaf(a, tsum, acc1);
    else       acc0 = fmaf(a, tsum, acc0);
  }
  return acc0 + acc1;
}

__global__ __launch_bounds__(512) void tp_kernel(
    const float* __restrict__ in1, const float* __restrict__ in2,
    const float* __restrict__ table, float* __restrict__ out) {
  __shared__ float s1[64 * PAD];   // [dim][batch] transposed, padded
  __shared__ float s2[64 * PAD];
  __shared__ float so[16 * PAD];   // quarter of the 64x64 output tile

  const int tid = threadIdx.x;
  const int b0 = blockIdx.x << 6;   // batch tile (64)
  const int h0 = blockIdx.y << 6;   // h tile (64)
  const int w = tid >> 6;           // wave id 0..7: owns local rows w+8k
  const int t = tid & 63;           // lane = batch element

  // wave's cb-table rows; lane t holds entry t of each row. Row local w+8j
  // lives at tb[j<<9]. Prefetch phase 0's pair now (latency hidden by staging).
  const float* tb = table + ((size_t)(h0 + w) << 6) + t;
  float cur0 = tb[0];
  float cur1 = tb[512];

  // ---- stage in1/in2 tiles into LDS, transposed [d][b] ----
  const float4* g1 = reinterpret_cast<const float4*>(in1 + (size_t)b0 * 64);
  const float4* g2 = reinterpret_cast<const float4*>(in2 + (size_t)b0 * 64);
#pragma unroll
  for (int r = 0; r < 2; ++r) {
    int idx4 = r * 512 + tid;          // float4 index into 64x64 tile
    float4 v1 = g1[idx4];
    float4 v2 = g2[idx4];
    int bl = idx4 >> 4;                // batch row (16 float4 per row)
    int d0 = (idx4 & 15) << 2;         // dim start
    s1[(d0 + 0) * PAD + bl] = v1.x; s1[(d0 + 1) * PAD + bl] = v1.y;
    s1[(d0 + 2) * PAD + bl] = v1.z; s1[(d0 + 3) * PAD + bl] = v1.w;
    s2[(d0 + 0) * PAD + bl] = v2.x; s2[(d0 + 1) * PAD + bl] = v2.y;
    s2[(d0 + 2) * PAD + bl] = v2.z; s2[(d0 + 3) * PAD + bl] = v2.w;
  }
  __syncthreads();

#pragma unroll 1
  for (int q = 0; q < 4; ++q) {
    // prefetch next phase's two rows (clamped dummy on last phase)
    int joff = (q < 3) ? ((2 * q + 2) << 9) : 0;
    float nxt0 = tb[joff];
    float nxt1 = tb[joff + 512];

#pragma unroll 1
    for (int m = 0; m < 2; ++m) {
      float vrow = m ? cur1 : cur0;
      int h = __builtin_amdgcn_readfirstlane(h0 + 16 * q + 8 * m + w);
      int i1, i2, n1, n2, l1l2;
      decode_h(h, i1, i2, n1, n2, l1l2);

      float acc = 0.f;
#define TP_CASE(L1, L2) \
      case (L1 * 4 + L2): acc = inner_tp<2 * L1 + 1, 2 * L2 + 1>(vrow, s1, s2, i1, i2, t); break;
      switch (l1l2) {
        TP_CASE(0, 0) TP_CASE(0, 1) TP_CASE(0, 2) TP_CASE(0, 3)
        TP_CASE(1, 0) TP_CASE(1, 1) TP_CASE(1, 2) TP_CASE(1, 3)
        TP_CASE(2, 0) TP_CASE(2, 1) TP_CASE(2, 2) TP_CASE(2, 3)
        TP_CASE(3, 0) TP_CASE(3, 1) TP_CASE(3, 2) TP_CASE(3, 3)
        default: break;
      }
#undef TP_CASE
      so[(8 * m + w) * PAD + t] = acc;
    }
    __syncthreads();

    // ---- flush quarter: 16 h-rows x 64 batches; each thread one float2 ----
    {
      const int bl = tid >> 3;            // batch row 0..63
      const int hseg = (tid & 7) << 1;    // 0,2,...,14
      float2 v;
      v.x = so[(hseg + 0) * PAD + bl];
      v.y = so[(hseg + 1) * PAD + bl];
      *reinterpret_cast<float2*>(out + (size_t)(b0 + bl) * 4096 + h0 + 16 * q + hseg) = v;
    }
    if (q < 3) __syncthreads();   // so reused next phase
    cur0 = nxt0;
    cur1 = nxt1;
  }
}

extern "C" void kernel_launch(void* const* d_in, const int* in_sizes, int n_in,
                              void* d_out, int out_size, void* d_ws, size_t ws_size,
                              hipStream_t stream) {
  const float* in1 = (const float*)d_in[0];
  const float* in2 = (const float*)d_in[1];
  const float* cb  = (const float*)d_in[2];
  float* out = (float*)d_out;
  float* table = (float*)d_ws;   // 4096*64*4 = 1 MB
  (void)in_sizes; (void)n_in; (void)out_size; (void)ws_size;
  prep_kernel<<<1024, 256, 0, stream>>>(cb, table);
  tp_kernel<<<dim3(64, 64), 512, 0, stream>>>(in1, in2, table, out);
}

// Round 5
// 140.906 us; speedup vs baseline: 1.6594x; 1.1282x over previous
//
#include <hip/hip_runtime.h>

// out[b,h] = sum_{i,j} cb[h, i*64+j] * in1[b,i] * in2[b,j]
// B = 4096, dim1 = dim2 = 64, H = 4096.
//
// Round-4 structure:
//   prep_kernel: table[h][0..63] = compacted cb row (d_ws), plus
//                meta[h] = i1 | i2<<8 | l1l2<<16 (decode done once, not
//                per batch-tile -> kills ~30 VALU/row in the hot kernel).
//   tp_kernel: 512 thr (8 waves), 64b x 64h tile, so-quarter flushes.
//     - LDS x-tiles in [batch][dim] layout, stride 65 (bank-rotated):
//       bb/aa reads are lane-adjacent -> ds_read2_b32 (2 vals/instr),
//       halving LDS-pipe pressure vs round 3's strided b32 reads.
//     - cb rows + meta prefetched one phase ahead (regs / s_loads).
//     - flush: 256 threads x float4 -> full 64B line segments.

#define SDIM 65   // s1/s2 row stride: bank = (t + d) % 32, 2-way max (free)
#define SOP  65   // so row stride

__constant__ int   kStart[7] = {0, 64, 496, 1376, 2496, 3360, 3888};
__constant__ unsigned kMagic[7] = {262144u, 87382u, 52429u, 37450u, 29128u, 23832u, 20165u}; // 2^18/d rounded up, d=2*l3+1
__constant__ int   kVpOff[7] = {0, 4, 13, 24, 34, 40, 43};
__constant__ unsigned char kVp[44] = {
  0, 5, 10, 15,                                  // l3=0
  1, 4, 5, 6, 9, 10, 11, 14, 15,                 // l3=1
  2, 5, 6, 7, 8, 9, 10, 11, 13, 14, 15,          // l3=2 ((1,3) before (2,0))
  3, 6, 7, 9, 10, 11, 12, 13, 14, 15,            // l3=3 ((2,3) before (3,0))
  7, 10, 11, 13, 14, 15,                         // l3=4
  11, 14, 15,                                    // l3=5
  15};                                           // l3=6
__constant__ int kBase[4] = {0, 4, 16, 36};  // offset of first slot of each l

__device__ __forceinline__ void decode_h(int h, int& i1, int& i2,
                                         int& n1, int& n2, int& l1l2) {
  int l3 = (h >= 64) + (h >= 496) + (h >= 1376) + (h >= 2496) + (h >= 3360) + (h >= 3888);
  unsigned hl = (unsigned)(h - kStart[l3]);
  int pair = (int)((hl * kMagic[l3]) >> 18);   // hl / (2*l3+1), exact in range
  int slot = pair & 15;
  int vp   = pair >> 4;
  l1l2 = (int)kVp[kVpOff[l3] + vp];
  int l1 = l1l2 >> 2, l2 = l1l2 & 3;
  n1 = 2 * l1 + 1;
  n2 = 2 * l2 + 1;
  i1 = kBase[l1] + (slot >> 2) * n1;
  i2 = kBase[l2] + (slot & 3) * n2;
}

// ---- prep: compact cb rows + decode metadata ----
__global__ __launch_bounds__(256) void prep_kernel(const float* __restrict__ cb,
                                                   float* __restrict__ table,
                                                   int* __restrict__ meta) {
  int idx = blockIdx.x * 256 + threadIdx.x;   // 1024 blocks -> 262144 = 4096*64
  int h = idx >> 6, e = idx & 63;
  int i1, i2, n1, n2, c;
  decode_h(h, i1, i2, n1, n2, c);
  if (e == 0) meta[h] = i1 | (i2 << 8) | (c << 16);
  unsigned mg = (n2 == 1) ? 65536u : (n2 == 3) ? 21846u : (n2 == 5) ? 13108u : 9363u;
  int qi = (int)(((unsigned)e * mg) >> 16);   // e / n2, exact for e < 64
  int rj = e - qi * n2;
  float v = 0.f;
  if (e < n1 * n2) v = cb[(size_t)h * 4096 + (i1 + qi) * 64 + (i2 + rj)];
  table[(size_t)h * 64 + e] = v;
}

__device__ __forceinline__ float lane_bcast(float v, int l) {
  union { float f; int i; } u;
  u.f = v;
  u.i = __builtin_amdgcn_readlane(u.i, l);
  return u.f;
}

template <int N1, int N2>
__device__ __forceinline__ float inner_tp(float vrow,
                                          const float* __restrict__ s1r,
                                          const float* __restrict__ s2r,
                                          int i1, int i2) {
  float bb[N2], aa[N1];
#pragma unroll
  for (int j = 0; j < N2; ++j) bb[j] = s2r[i2 + j];   // adjacent -> ds_read2_b32
#pragma unroll
  for (int i = 0; i < N1; ++i) aa[i] = s1r[i1 + i];   // adjacent -> ds_read2_b32
  float acc0 = 0.f, acc1 = 0.f;
#pragma unroll
  for (int i = 0; i < N1; ++i) {
    float tsum = lane_bcast(vrow, i * N2) * bb[0];
#pragma unroll
    for (int j = 1; j < N2; ++j) tsum = fmaf(lane_bcast(vrow, i * N2 + j), bb[j], tsum);
    if (i & 1) acc1 = fmaf(aa[i], tsum, acc1);
    else       acc0 = fmaf(aa[i], tsum, acc0);
  }
  return acc0 + acc1;
}

__global__ __launch_bounds__(512) void tp_kernel(
    const float* __restrict__ in1, const float* __restrict__ in2,
    const float* __restrict__ table, const int* __restrict__ meta,
    float* __restrict__ out) {
  __shared__ float s1[64 * SDIM];   // [batch][dim], stride 65
  __shared__ float s2[64 * SDIM];
  __shared__ float so[16 * SOP];    // quarter of the 64x64 output tile

  const int tid = threadIdx.x;
  const int b0 = blockIdx.x << 6;   // batch tile (64)
  const int h0 = blockIdx.y << 6;   // h tile (64)
  const int w = tid >> 6;           // wave id 0..7
  const int t = tid & 63;           // lane = batch element

  // cb-table rows for this wave (lane t holds entry t); local row 8m+w of
  // quarter q sits at tb[(2q+m)<<9]. Prefetch phase 0 now.
  const float* tb = table + ((size_t)(h0 + w) << 6) + t;
  float cur0 = tb[0];
  float cur1 = tb[512];
  int mcur0 = meta[__builtin_amdgcn_readfirstlane(h0 + w)];        // s_load
  int mcur1 = meta[__builtin_amdgcn_readfirstlane(h0 + 8 + w)];

  // ---- stage in1/in2 tiles into LDS, [batch][dim] (no transpose) ----
  const float4* g1 = reinterpret_cast<const float4*>(in1 + (size_t)b0 * 64);
  const float4* g2 = reinterpret_cast<const float4*>(in2 + (size_t)b0 * 64);
#pragma unroll
  for (int r = 0; r < 2; ++r) {
    int idx4 = r * 512 + tid;          // float4 index into 64x64 tile
    float4 v1 = g1[idx4];
    float4 v2 = g2[idx4];
    int bl = idx4 >> 4;                // batch row (16 float4 per row)
    int d0 = (idx4 & 15) << 2;         // dim start
    float* p1 = &s1[bl * SDIM + d0];
    float* p2 = &s2[bl * SDIM + d0];
    p1[0] = v1.x; p1[1] = v1.y; p1[2] = v1.z; p1[3] = v1.w;
    p2[0] = v2.x; p2[1] = v2.y; p2[2] = v2.z; p2[3] = v2.w;
  }
  __syncthreads();

  const float* s1r = &s1[t * SDIM];
  const float* s2r = &s2[t * SDIM];

#pragma unroll 1
  for (int q = 0; q < 4; ++q) {
    // prefetch next phase (clamped to phase 0 on the last iteration)
    int joff = (q < 3) ? ((2 * q + 2) << 9) : 0;
    float nxt0 = tb[joff];
    float nxt1 = tb[joff + 512];
    int mj = (q < 3) ? (16 * (q + 1)) : 0;
    int mnxt0 = meta[__builtin_amdgcn_readfirstlane(h0 + mj + w)];
    int mnxt1 = meta[__builtin_amdgcn_readfirstlane(h0 + mj + 8 + w)];

#pragma unroll 1
    for (int m = 0; m < 2; ++m) {
      float vrow = m ? cur1 : cur0;
      int mm = m ? mcur1 : mcur0;
      int i1 = mm & 255;
      int i2 = (mm >> 8) & 255;
      int l1l2 = (mm >> 16) & 255;

      float acc = 0.f;
#define TP_CASE(L1, L2) \
      case (L1 * 4 + L2): acc = inner_tp<2 * L1 + 1, 2 * L2 + 1>(vrow, s1r, s2r, i1, i2); break;
      switch (l1l2) {
        TP_CASE(0, 0) TP_CASE(0, 1) TP_CASE(0, 2) TP_CASE(0, 3)
        TP_CASE(1, 0) TP_CASE(1, 1) TP_CASE(1, 2) TP_CASE(1, 3)
        TP_CASE(2, 0) TP_CASE(2, 1) TP_CASE(2, 2) TP_CASE(2, 3)
        TP_CASE(3, 0) TP_CASE(3, 1) TP_CASE(3, 2) TP_CASE(3, 3)
        default: break;
      }
#undef TP_CASE
      so[(8 * m + w) * SOP + t] = acc;
    }
    __syncthreads();

    // ---- flush quarter: 16 h-rows x 64 batches; 256 threads x float4 ----
    if (tid < 256) {
      int bl = tid >> 2;               // batch row 0..63
      int hs = (tid & 3) << 2;         // h offset 0,4,8,12
      const float* sp = &so[hs * SOP + bl];
      float4 v;
      v.x = sp[0];
      v.y = sp[SOP];
      v.z = sp[2 * SOP];
      v.w = sp[3 * SOP];
      *reinterpret_cast<float4*>(out + (size_t)(b0 + bl) * 4096 + h0 + 16 * q + hs) = v;
    }
    if (q < 3) __syncthreads();   // so reused next phase
    cur0 = nxt0; cur1 = nxt1;
    mcur0 = mnxt0; mcur1 = mnxt1;
  }
}

extern "C" void kernel_launch(void* const* d_in, const int* in_sizes, int n_in,
                              void* d_out, int out_size, void* d_ws, size_t ws_size,
                              hipStream_t stream) {
  const float* in1 = (const float*)d_in[0];
  const float* in2 = (const float*)d_in[1];
  const float* cb  = (const float*)d_in[2];
  float* out = (float*)d_out;
  float* table = (float*)d_ws;                       // 4096*64*4 = 1 MB
  int* meta = (int*)((char*)d_ws + (size_t)4096 * 64 * 4);   // +16 KB
  (void)in_sizes; (void)n_in; (void)out_size; (void)ws_size;
  prep_kernel<<<1024, 256, 0, stream>>>(cb, table, meta);
  tp_kernel<<<dim3(64, 64), 512, 0, stream>>>(in1, in2, table, meta, out);
}